// Round 3
// baseline (528.422 us; speedup 1.0000x reference)
//
#include <hip/hip_runtime.h>
#include <hip/hip_cooperative_groups.h>

namespace cg = cooperative_groups;

#define TPB 256
#define MAXBLK 1024

typedef __attribute__((ext_vector_type(8))) short short8;
typedef __attribute__((ext_vector_type(4))) float floatx4;

__device__ __forceinline__ unsigned short bf_trunc(float f){
    union { float f; unsigned u; } c; c.f = f;
    return (unsigned short)(c.u >> 16);
}
__device__ __forceinline__ unsigned short bf_rne(float f){
    union { float f; unsigned u; } c; c.f = f;
    unsigned r = c.u + 0x7fffu + ((c.u >> 16) & 1u);
    return (unsigned short)(r >> 16);
}

struct Params {
    const float* feats; const int* bidx;
    const float* w1; const float* b1;
    const float* gamma; const float* beta;
    const float* w2; const float* b2;
    const float* mw1; const float* mb1;
    const float* mw2; const float* mb2;
    const float* iw; const float* ib;
    float* pt; float* mask; float* pooled; float* iou;
    float* ws_sum; float* ws_sq; float* ws_pool;
    int N; int B;
};

// ---------------------------------------------------------------------------
// Single cooperative kernel.
//  phase1: transposed MFMA D = W^T * feats^T; stats (reg accum), mask branch
//          (relu -> dot -> 2 shfl_xor), pooled per-batch sums (sorted runs).
//  grid.sync()
//  fold:   every block recomputes BN scale s[ch], folded bias b'[ch] from the
//          global stats (32 ch, trivial) -- no separate finalize dispatch.
//          block 0 additionally writes pooled + iou (counts via binary search).
//  phase2: refolded-weight MFMA, relu, 32x3 projection -> pt_offsets.
//          Same wave -> same row span in both phases (L2/L3 locality).
// ---------------------------------------------------------------------------
__global__ __launch_bounds__(TPB, 4) void inst_head_fused(Params P)
{
    __shared__ float s_pool[8][32];
    __shared__ float s_sum[32];
    __shared__ float s_sq[32];
    __shared__ float s_sc[32];     // BN scale per channel (phase2)
    __shared__ float s_bp[32];     // folded bias per channel (phase2)
    __shared__ float s_pooled[256];
    __shared__ int   s_lb[33];

    const int tid  = threadIdx.x;
    const int lane = tid & 63;
    const int p = lane & 15;               // MFMA col = point-in-tile / A-row
    const int q = lane >> 4;               // k-group

    const int N = P.N, B = P.B;

    if (tid < 32){ s_sum[tid] = 0.f; s_sq[tid] = 0.f; }
    ((float*)s_pool)[tid] = 0.f;
    __syncthreads();

    // ---- phase-1 constants: weight A-frags + bias C-inits (registers) ----
    short8 aw0, aw1, am0, am1;
    floatx4 ci_h0, ci_h1, ci_m0, ci_m1;
    float mw2v[8];
#pragma unroll
    for (int j = 0; j < 8; ++j){
        const int k = q * 8 + j;
        aw0[j] = (short)bf_rne(P.w1 [k * 32 + p]);
        aw1[j] = (short)bf_rne(P.w1 [k * 32 + 16 + p]);
        am0[j] = (short)bf_rne(P.mw1[k * 32 + p]);
        am1[j] = (short)bf_rne(P.mw1[k * 32 + 16 + p]);
    }
#pragma unroll
    for (int r = 0; r < 4; ++r){
        const int c0 = q * 4 + r, c1 = 16 + q * 4 + r;
        ci_h0[r] = P.b1[c0];  ci_h1[r] = P.b1[c1];
        ci_m0[r] = P.mb1[c0]; ci_m1[r] = P.mb1[c1];
        mw2v[r] = P.mw2[c0];  mw2v[4 + r] = P.mw2[c1];
    }
    const float mb2s = P.mb2[0];

    float hsum[8] = {0,0,0,0,0,0,0,0};
    float hsq [8] = {0,0,0,0,0,0,0,0};
    float pacc[8] = {0,0,0,0,0,0,0,0};
    int curb = -1;

    const int  ntiles = (N + 15) >> 4;
    const long nw  = (long)gridDim.x * (TPB / 64);
    const long wid = (long)blockIdx.x * (TPB / 64) + (tid >> 6);
    const int  t0 = (int)(wid * (long)ntiles / nw);
    const int  t1 = (int)((wid + 1) * (long)ntiles / nw);

    for (int t = t0; t < t1; ++t){
        const int row0 = t << 4;
        const int row  = row0 + p;
        const bool valid = (row < N);

        floatx4 v0 = {0.f,0.f,0.f,0.f}, v1 = {0.f,0.f,0.f,0.f};
        if (valid){
            const floatx4* rp = (const floatx4*)(P.feats + (size_t)row * 32 + q * 8);
            v0 = rp[0]; v1 = rp[1];
        }

        const int b = valid ? P.bidx[row] : -1;
        if (b != curb){
            if (curb >= 0){
#pragma unroll
                for (int j = 0; j < 8; ++j){
                    atomicAdd(&s_pool[curb][q * 8 + j], pacc[j]);
                    pacc[j] = 0.f;
                }
            }
            curb = b;
        }
        if (b >= 0){
            pacc[0] += v0[0]; pacc[1] += v0[1]; pacc[2] += v0[2]; pacc[3] += v0[3];
            pacc[4] += v1[0]; pacc[5] += v1[1]; pacc[6] += v1[2]; pacc[7] += v1[3];
        }

        short8 bfrag;
        bfrag[0] = (short)bf_trunc(v0[0]); bfrag[1] = (short)bf_trunc(v0[1]);
        bfrag[2] = (short)bf_trunc(v0[2]); bfrag[3] = (short)bf_trunc(v0[3]);
        bfrag[4] = (short)bf_trunc(v1[0]); bfrag[5] = (short)bf_trunc(v1[1]);
        bfrag[6] = (short)bf_trunc(v1[2]); bfrag[7] = (short)bf_trunc(v1[3]);

        const floatx4 ch0 = __builtin_amdgcn_mfma_f32_16x16x32_bf16(aw0, bfrag, ci_h0, 0, 0, 0);
        const floatx4 ch1 = __builtin_amdgcn_mfma_f32_16x16x32_bf16(aw1, bfrag, ci_h1, 0, 0, 0);
        const floatx4 cm0 = __builtin_amdgcn_mfma_f32_16x16x32_bf16(am0, bfrag, ci_m0, 0, 0, 0);
        const floatx4 cm1 = __builtin_amdgcn_mfma_f32_16x16x32_bf16(am1, bfrag, ci_m1, 0, 0, 0);

        if (valid){
#pragma unroll
            for (int r = 0; r < 4; ++r){
                const float h0 = ch0[r]; hsum[r]     += h0; hsq[r]     = fmaf(h0, h0, hsq[r]);
                const float h1 = ch1[r]; hsum[4 + r] += h1; hsq[4 + r] = fmaf(h1, h1, hsq[4 + r]);
            }
        }

        float tm = 0.f;
#pragma unroll
        for (int r = 0; r < 4; ++r){
            tm = fmaf(fmaxf(cm0[r], 0.f), mw2v[r],     tm);
            tm = fmaf(fmaxf(cm1[r], 0.f), mw2v[4 + r], tm);
        }
        tm += __shfl_xor(tm, 16, 64);
        tm += __shfl_xor(tm, 32, 64);
        if (q == 0 && valid) P.mask[row] = tm + mb2s;
    }

    if (curb >= 0){
#pragma unroll
        for (int j = 0; j < 8; ++j) atomicAdd(&s_pool[curb][q * 8 + j], pacc[j]);
    }
#pragma unroll
    for (int i = 0; i < 8; ++i){
        const int ch = (i >> 2) * 16 + q * 4 + (i & 3);
        atomicAdd(&s_sum[ch], hsum[i]);
        atomicAdd(&s_sq[ch],  hsq[i]);
    }
    __syncthreads();
    if (tid < 32){
        atomicAdd(&P.ws_sum[tid], s_sum[tid]);
        atomicAdd(&P.ws_sq[tid],  s_sq[tid]);
    }
    {
        const float pv = ((float*)s_pool)[tid];
        if (pv != 0.f) atomicAdd(&P.ws_pool[tid], pv);
    }

    // ================= grid-wide barrier: stats complete =================
    cg::this_grid().sync();

    // ---- block 0: pooled + iou outputs ----
    if (blockIdx.x == 0){
        if (tid <= B){
            int lo = 0, hi = N;
            while (lo < hi){
                const int mid = (lo + hi) >> 1;
                if (P.bidx[mid] < tid) lo = mid + 1; else hi = mid;
            }
            s_lb[tid] = lo;
        }
        __syncthreads();
        if (tid < B * 32){
            const int bb = tid >> 5;
            const float cnt = fmaxf((float)(s_lb[bb + 1] - s_lb[bb]), 1.f);
            const float pv = P.ws_pool[tid] / cnt;
            s_pooled[tid] = pv;
            P.pooled[tid] = pv;
        }
        __syncthreads();
        if (tid < B){
            float acc = P.ib[0];
#pragma unroll
            for (int i = 0; i < 32; ++i) acc = fmaf(s_pooled[tid * 32 + i], P.iw[i], acc);
            P.iou[tid] = acc;
        }
    }

    // ---- every block: recompute BN fold locally (32 channels, trivial) ----
    if (tid < 32){
        const float invN = 1.f / (float)N;
        const float mu  = P.ws_sum[tid] * invN;
        const float var = P.ws_sq[tid] * invN - mu * mu;
        const float s   = P.gamma[tid] * rsqrtf(var + 1e-4f);
        s_sc[tid] = s;
        s_bp[tid] = (P.b1[tid] - mu) * s + P.beta[tid];
    }
    __syncthreads();

    // ---- phase-2 constants: folded weight A-frags, biases, W2 ----
    short8 pw0, pw1;
    floatx4 pc0, pc1;
    float w2v[24];
    const float sc0 = s_sc[p], sc1 = s_sc[16 + p];
#pragma unroll
    for (int j = 0; j < 8; ++j){
        const int k = q * 8 + j;
        pw0[j] = (short)bf_rne(P.w1[k * 32 + p]      * sc0);
        pw1[j] = (short)bf_rne(P.w1[k * 32 + 16 + p] * sc1);
    }
#pragma unroll
    for (int r = 0; r < 4; ++r){
        pc0[r] = s_bp[q * 4 + r];
        pc1[r] = s_bp[16 + q * 4 + r];
    }
#pragma unroll
    for (int i = 0; i < 8; ++i){
        const int ch = (i >> 2) * 16 + q * 4 + (i & 3);
        w2v[i]      = P.w2[ch * 3 + 0];
        w2v[8 + i]  = P.w2[ch * 3 + 1];
        w2v[16 + i] = P.w2[ch * 3 + 2];
    }
    const float b2v0 = P.b2[0], b2v1 = P.b2[1], b2v2 = P.b2[2];

    for (int t = t0; t < t1; ++t){
        const int row0 = t << 4;
        const int row  = row0 + p;
        const bool valid = (row < N);

        floatx4 v0 = {0.f,0.f,0.f,0.f}, v1 = {0.f,0.f,0.f,0.f};
        if (valid){
            const floatx4* rp = (const floatx4*)(P.feats + (size_t)row * 32 + q * 8);
            v0 = rp[0]; v1 = rp[1];
        }
        short8 bfrag;
        bfrag[0] = (short)bf_trunc(v0[0]); bfrag[1] = (short)bf_trunc(v0[1]);
        bfrag[2] = (short)bf_trunc(v0[2]); bfrag[3] = (short)bf_trunc(v0[3]);
        bfrag[4] = (short)bf_trunc(v1[0]); bfrag[5] = (short)bf_trunc(v1[1]);
        bfrag[6] = (short)bf_trunc(v1[2]); bfrag[7] = (short)bf_trunc(v1[3]);

        const floatx4 c0 = __builtin_amdgcn_mfma_f32_16x16x32_bf16(pw0, bfrag, pc0, 0, 0, 0);
        const floatx4 c1 = __builtin_amdgcn_mfma_f32_16x16x32_bf16(pw1, bfrag, pc1, 0, 0, 0);

        float s0 = 0.f, s1 = 0.f, s2 = 0.f;
#pragma unroll
        for (int r = 0; r < 4; ++r){
            const float p0 = fmaxf(c0[r], 0.f);
            const float p1 = fmaxf(c1[r], 0.f);
            s0 = fmaf(p0, w2v[r],      s0); s0 = fmaf(p1, w2v[4 + r],  s0);
            s1 = fmaf(p0, w2v[8 + r],  s1); s1 = fmaf(p1, w2v[12 + r], s1);
            s2 = fmaf(p0, w2v[16 + r], s2); s2 = fmaf(p1, w2v[20 + r], s2);
        }
        s0 += __shfl_xor(s0, 16, 64); s0 += __shfl_xor(s0, 32, 64);
        s1 += __shfl_xor(s1, 16, 64); s1 += __shfl_xor(s1, 32, 64);
        s2 += __shfl_xor(s2, 16, 64); s2 += __shfl_xor(s2, 32, 64);

        if (lane < 48 && valid){
            float val = (q == 0) ? (s0 + b2v0) : ((q == 1) ? (s1 + b2v1) : (s2 + b2v2));
            P.pt[(size_t)row0 * 3 + p * 3 + q] = val;
        }
    }
}

extern "C" void kernel_launch(void* const* d_in, const int* in_sizes, int n_in,
                              void* d_out, int out_size, void* d_ws, size_t ws_size,
                              hipStream_t stream) {
    Params P;
    P.feats = (const float*)d_in[0];
    P.bidx  = (const int*)d_in[1];
    P.w1    = (const float*)d_in[2];
    P.b1    = (const float*)d_in[3];
    P.gamma = (const float*)d_in[4];
    P.beta  = (const float*)d_in[5];
    P.w2    = (const float*)d_in[6];
    P.b2    = (const float*)d_in[7];
    P.mw1   = (const float*)d_in[8];
    P.mb1   = (const float*)d_in[9];
    P.mw2   = (const float*)d_in[10];
    P.mb2   = (const float*)d_in[11];
    P.iw    = (const float*)d_in[12];
    P.ib    = (const float*)d_in[13];

    const int N = in_sizes[0] / 32;
    const int B = (out_size - 4 * N) / 33;   // out = 3N + N + 32B + B
    P.N = N; P.B = B;

    float* out = (float*)d_out;
    P.pt     = out;
    P.mask   = out + (size_t)3 * N;
    P.pooled = out + (size_t)4 * N;
    P.iou    = P.pooled + (size_t)B * 32;

    float* ws = (float*)d_ws;
    P.ws_sum  = ws;
    P.ws_sq   = ws + 32;
    P.ws_pool = ws + 64;

    hipMemsetAsync(ws, 0, (size_t)(64 + B * 32) * sizeof(float), stream);

    // size the cooperative grid so all blocks are co-resident
    int dev = 0;
    hipGetDevice(&dev);
    hipDeviceProp_t prop;
    hipGetDeviceProperties(&prop, dev);
    int perCU = 0;
    hipOccupancyMaxActiveBlocksPerMultiprocessor(&perCU, inst_head_fused, TPB, 0);
    int grid = perCU * prop.multiProcessorCount;
    if (grid > MAXBLK) grid = MAXBLK;
    if (grid < 1) grid = 1;

    void* args[] = { (void*)&P };
    hipLaunchCooperativeKernel((const void*)inst_head_fused,
                               dim3(grid), dim3(TPB), args, 0, stream);
}